// Round 1
// 351.151 us; speedup vs baseline: 1.3198x; 1.3198x over previous
//
#include <hip/hip_runtime.h>
#include <math.h>

// YOLOv5 head, fused single-kernel bf16 MFMA GEMM for all 3 scales.
//   D[hw][o] = sum_c p[b,c,hw] * w[o,c]   (p-frag as MFMA A, w-frag as MFMA B)
// so D's lane axis = o -> 16-lane coalesced 64B stores in the decode epilogue.
// K-loop: double-buffered LDS, ONE raw barrier per 32-K step, global loads for
// step i+1 issued at step i and kept in flight across the barrier (no vmcnt drain).

#define NOUT 85
#define TOTAL_ROWS 25200

typedef __attribute__((ext_vector_type(8))) short short8;
typedef __attribute__((ext_vector_type(4))) float floatx4;

__device__ __forceinline__ unsigned short f2bf(float x) {
    union { float f; unsigned u; } v; v.f = x;
    unsigned r = v.u + 0x7fffu + ((v.u >> 16) & 1u);  // RNE
    return (unsigned short)(r >> 16);
}

// ws layout (ushort units): wA0 @ 0 (256*256), wA1 @ 65536 (256*512), wA2 @ 196608 (256*1024)
__global__ __launch_bounds__(256) void convert_w_all(
    const float* __restrict__ w0, const float* __restrict__ w1,
    const float* __restrict__ w2, unsigned short* __restrict__ dst)
{
    int i = blockIdx.x * 256 + threadIdx.x;   // 0 .. 458751
    const float* w; int C, idx;
    if (i < 65536)       { w = w0; C = 256;  idx = i; }
    else if (i < 196608) { w = w1; C = 512;  idx = i - 65536; }
    else                 { w = w2; C = 1024; idx = i - 196608; }
    int m = idx / C, c = idx - m * C;
    float v = (m < 255) ? w[(size_t)m * C + c] : 0.f;   // row 255 = zero pad
    dst[i] = f2bf(v);
}

__global__ __launch_bounds__(256) void yolo_fused(
    const float* __restrict__ p0, const float* __restrict__ p1,
    const float* __restrict__ p2, const unsigned short* __restrict__ wsA,
    const float* __restrict__ b0v, const float* __restrict__ b1v,
    const float* __restrict__ b2v, const float* __restrict__ anc,  // [3,3,2]
    float* __restrict__ out)
{
    __shared__ __align__(16) unsigned short Bl[2][64 * 32];  // double-buffered [hw][k] bf16

    const int tid = threadIdx.x;
    const int l   = tid & 63;
    const int wv  = tid >> 6;          // wave id: o-stripe [64*wv, 64*wv+64)
    const int ml  = l & 15;
    const int q   = l >> 4;

    // scale select: scale2 blocks first (longest K -> start earliest)
    const int x = blockIdx.x;
    const float* p; const unsigned short* wA; const float* bias; const float* an;
    int C, HW, row_off, sh, tile, b; float stride_;
    if (x < 112) {                       // scale 2: 7 tiles x 16 b
        b = x / 7;  tile = x - b * 7;
        p = p2; wA = wsA + 196608; bias = b2v; an = anc + 12;
        C = 1024; HW = 400; row_off = 24000; sh = 2; stride_ = 32.f;
    } else if (x < 512) {                // scale 1: 25 x 16
        int i = x - 112; b = i / 25; tile = i - b * 25;
        p = p1; wA = wsA + 65536; bias = b1v; an = anc + 6;
        C = 512; HW = 1600; row_off = 19200; sh = 3; stride_ = 16.f;
    } else {                             // scale 0: 100 x 16
        int i = x - 512; b = i / 100; tile = i - b * 100;
        p = p0; wA = wsA; bias = b0v; an = anc;
        C = 256; HW = 6400; row_off = 0; sh = 4; stride_ = 8.f;
    }
    const int hw0   = tile * 64;
    const int iters = C >> 5;

    floatx4 acc[4][4];                   // [ni(hw)][mi(o)]
#pragma unroll
    for (int ni = 0; ni < 4; ++ni)
#pragma unroll
        for (int mi = 0; mi < 4; ++mi)
            acc[ni][mi] = floatx4{0.f, 0.f, 0.f, 0.f};

    const float* pb = p + (size_t)b * C * HW;
    int scol = hw0 + l; if (scol >= HW) scol = HW - 1;   // clamp (scale2 tail)
    const float* pcur = pb + (size_t)(wv * 8) * HW + scol;
    const size_t kjump = (size_t)32 * HW;

    // LDS chunk swizzle: row r, 16B-chunk c holds k-octet (c ^ (r&3) ^ ((r>>2)&3))
    const int wchunk = wv ^ (l & 3) ^ ((l >> 2) & 3);
    // w-frag base: row o = wv*64 + mi*16 + ml, bytes [k0 + q*8 ..)
    const unsigned short* wbase = wA + (size_t)(wv * 64 + ml) * C + q * 8;

    // ---- prologue: stage k-step 0, prefetch k-step 1 ----
    float bv[8];
#pragma unroll
    for (int r = 0; r < 8; ++r) bv[r] = pcur[(size_t)r * HW];
    pcur += kjump;
    {
        unsigned pk0 = (unsigned)f2bf(bv[0]) | ((unsigned)f2bf(bv[1]) << 16);
        unsigned pk1 = (unsigned)f2bf(bv[2]) | ((unsigned)f2bf(bv[3]) << 16);
        unsigned pk2 = (unsigned)f2bf(bv[4]) | ((unsigned)f2bf(bv[5]) << 16);
        unsigned pk3 = (unsigned)f2bf(bv[6]) | ((unsigned)f2bf(bv[7]) << 16);
        ((uint4*)Bl[0])[l * 4 + wchunk] = make_uint4(pk0, pk1, pk2, pk3);
    }
#pragma unroll
    for (int r = 0; r < 8; ++r) bv[r] = pcur[(size_t)r * HW];
    pcur += kjump;
    asm volatile("s_waitcnt lgkmcnt(0)" ::: "memory");
    __builtin_amdgcn_s_barrier();
    asm volatile("" ::: "memory");

    // ---- main loop: one barrier per 32-K step ----
    for (int it = 0; it < iters; ++it) {
        const unsigned short* Bc = Bl[it & 1];
        short8 wf[4];
#pragma unroll
        for (int mi = 0; mi < 4; ++mi)
            wf[mi] = *(const short8*)(wbase + (size_t)(mi * 16) * C + it * 32);
        short8 pf[4];
#pragma unroll
        for (int ni = 0; ni < 4; ++ni) {
            int n  = ni * 16 + ml;
            int ck = q ^ (n & 3) ^ ((n >> 2) & 3);
            pf[ni] = *(const short8*)(Bc + n * 32 + ck * 8);
        }
        if (it + 1 < iters) {            // stage next k-step (uses loads from last iter)
            unsigned pk0 = (unsigned)f2bf(bv[0]) | ((unsigned)f2bf(bv[1]) << 16);
            unsigned pk1 = (unsigned)f2bf(bv[2]) | ((unsigned)f2bf(bv[3]) << 16);
            unsigned pk2 = (unsigned)f2bf(bv[4]) | ((unsigned)f2bf(bv[5]) << 16);
            unsigned pk3 = (unsigned)f2bf(bv[6]) | ((unsigned)f2bf(bv[7]) << 16);
            ((uint4*)Bl[(it & 1) ^ 1])[l * 4 + wchunk] = make_uint4(pk0, pk1, pk2, pk3);
            if (it + 2 < iters) {        // issue loads for k-step it+2, keep in flight
#pragma unroll
                for (int r = 0; r < 8; ++r) bv[r] = pcur[(size_t)r * HW];
                pcur += kjump;
            }
        }
        asm volatile("s_waitcnt lgkmcnt(0)" ::: "memory");
        __builtin_amdgcn_s_barrier();
        asm volatile("" ::: "memory");
#pragma unroll
        for (int ni = 0; ni < 4; ++ni)
#pragma unroll
            for (int mi = 0; mi < 4; ++mi)
                acc[ni][mi] = __builtin_amdgcn_mfma_f32_16x16x32_bf16(
                    pf[ni], wf[mi], acc[ni][mi], 0, 0, 0);
    }

    // ---- epilogue: D row = hw_rel = ni*16 + q*4 + r; col = o_rel = mi*16 + ml ----
    // lanes ml=0..15 write consecutive oo -> coalesced 64B store runs
    const int nx = 5 << sh;
#pragma unroll
    for (int mi = 0; mi < 4; ++mi) {
        const int  o     = wv * 64 + mi * 16 + ml;
        const bool valid = (o < 255);
        const int  osafe = valid ? o : 254;
        const int  a     = osafe / 85;
        const int  oo    = osafe - a * 85;
        const float bi   = bias[osafe];
        const float anw  = an[a * 2 + 0];
        const float anh  = an[a * 2 + 1];
        float* orow = out + ((size_t)b * TOTAL_ROWS + row_off + a * HW) * NOUT + oo;
#pragma unroll
        for (int ni = 0; ni < 4; ++ni) {
            const int hwb = hw0 + ni * 16 + q * 4;
            if (hwb >= HW) continue;     // uniform per wave (HW % 16 == 0)
#pragma unroll
            for (int r = 0; r < 4; ++r) {
                const int hw = hwb + r;
                float y = acc[ni][mi][r] + bi;
                float s = 1.f / (1.f + __expf(-y));
                float v;
                if (oo >= 4) {
                    v = s;
                } else {
                    unsigned gy = (unsigned)(((unsigned long long)(unsigned)(hw >> sh)
                                             * 0xCCCCCCCDull) >> 34);   // (hw>>sh)/5
                    int gx = hw - (int)gy * nx;
                    if (oo == 0)      v = (2.f * s + (float)gx - 0.5f) * stride_;
                    else if (oo == 1) v = (2.f * s + (float)gy - 0.5f) * stride_;
                    else { float t = 2.f * s; v = t * t * ((oo == 2) ? anw : anh); }
                }
                if (valid) orow[(size_t)hw * NOUT] = v;
            }
        }
    }
}

extern "C" void kernel_launch(void* const* d_in, const int* in_sizes, int n_in,
                              void* d_out, int out_size, void* d_ws, size_t ws_size,
                              hipStream_t stream) {
    const float* p0 = (const float*)d_in[0];
    const float* p1 = (const float*)d_in[1];
    const float* p2 = (const float*)d_in[2];
    const float* w0 = (const float*)d_in[3];
    const float* b0 = (const float*)d_in[4];
    const float* w1 = (const float*)d_in[5];
    const float* b1 = (const float*)d_in[6];
    const float* w2 = (const float*)d_in[7];
    const float* b2 = (const float*)d_in[8];
    const float* anc = (const float*)d_in[9];  // [3,3,2]
    float* out = (float*)d_out;

    unsigned short* wsA = (unsigned short*)d_ws;   // needs 917504 B

    convert_w_all<<<dim3(458752 / 256), dim3(256), 0, stream>>>(w0, w1, w2, wsA);

    // fused: 112 scale2 blocks + 400 scale1 + 1600 scale0 = 2112
    yolo_fused<<<dim3(2112), dim3(256), 0, stream>>>(
        p0, p1, p2, wsA, b0, b1, b2, anc, out);
}

// Round 2
// 339.907 us; speedup vs baseline: 1.3634x; 1.0331x over previous
//
#include <hip/hip_runtime.h>
#include <math.h>

// YOLOv5 head, fused single-kernel bf16 MFMA GEMM for all 3 scales.
//   D[hw][o] = sum_c p[b,c,hw] * w[o,c]   (p-frag = MFMA A, w-frag = MFMA B)
// Weights pre-packed FRAG-CONTIGUOUS: each 16(o)x32(k) B-tile = 1024B in exact
// lane order, so a wf load is one fully-coalesced 1KB dwordx4 (was 64-line scatter).
// K-loop: double-buffered LDS, one raw barrier per 32-K step, 2-deep activation
// prefetch + 1-deep weight prefetch via manually unrolled x2 loop (static regs).

#define NOUT 85
#define TOTAL_ROWS 25200

typedef __attribute__((ext_vector_type(8))) short short8;
typedef __attribute__((ext_vector_type(4))) float floatx4;

__device__ __forceinline__ unsigned short f2bf(float x) {
    union { float f; unsigned u; } v; v.f = x;
    unsigned r = v.u + 0x7fffu + ((v.u >> 16) & 1u);  // RNE
    return (unsigned short)(r >> 16);
}

// ws layout (ushort units): wA0 @ 0 (65536), wA1 @ 65536 (131072), wA2 @ 196608 (262144)
// Frag-contiguous: within a scale, tile t = kt*16 + ot (ot=o/16, kt=k/32) occupies
// shorts [t*512, t*512+512); lane l = (o%16) + 16*((k%32)/8) holds k%8 octet:
//   dst[t*512 + l*8 + j] = w[ot*16 + (l&15)][kt*32 + (l>>4)*8 + j]
__global__ __launch_bounds__(256) void convert_w_all(
    const float* __restrict__ w0, const float* __restrict__ w1,
    const float* __restrict__ w2, unsigned short* __restrict__ dst)
{
    int i = blockIdx.x * 256 + threadIdx.x;   // 0 .. 458751
    const float* w; int C, idx;
    if (i < 65536)       { w = w0; C = 256;  idx = i; }
    else if (i < 196608) { w = w1; C = 512;  idx = i - 65536; }
    else                 { w = w2; C = 1024; idx = i - 196608; }
    int j  = idx & 7;
    int l  = (idx >> 3) & 63;
    int t  = idx >> 9;
    int ot = t & 15, kt = t >> 4;
    int o  = ot * 16 + (l & 15);
    int k  = kt * 32 + (l >> 4) * 8 + j;
    float v = (o < 255) ? w[(size_t)o * C + k] : 0.f;   // rows 255+ = zero pad
    dst[i] = f2bf(v);
}

__global__ __launch_bounds__(256) void yolo_fused(
    const float* __restrict__ p0, const float* __restrict__ p1,
    const float* __restrict__ p2, const unsigned short* __restrict__ wsA,
    const float* __restrict__ b0v, const float* __restrict__ b1v,
    const float* __restrict__ b2v, const float* __restrict__ anc,  // [3,3,2]
    float* __restrict__ out)
{
    __shared__ __align__(16) unsigned short Bl0[64 * 32];  // [hw][k] bf16, chunk-swizzled
    __shared__ __align__(16) unsigned short Bl1[64 * 32];

    const int tid = threadIdx.x;
    const int l   = tid & 63;
    const int wv  = tid >> 6;          // wave id: o-stripe [64*wv, 64*wv+64)
    const int ml  = l & 15;
    const int q   = l >> 4;

    // scale select: scale2 blocks first (longest K -> start earliest)
    const int x = blockIdx.x;
    const float* p; const unsigned short* wA; const float* bias; const float* an;
    int C, HW, row_off, sh, tile, b; float stride_;
    if (x < 112) {                       // scale 2: 7 tiles x 16 b
        b = x / 7;  tile = x - b * 7;
        p = p2; wA = wsA + 196608; bias = b2v; an = anc + 12;
        C = 1024; HW = 400; row_off = 24000; sh = 2; stride_ = 32.f;
    } else if (x < 512) {                // scale 1: 25 x 16
        int i = x - 112; b = i / 25; tile = i - b * 25;
        p = p1; wA = wsA + 65536; bias = b1v; an = anc + 6;
        C = 512; HW = 1600; row_off = 19200; sh = 3; stride_ = 16.f;
    } else {                             // scale 0: 100 x 16
        int i = x - 512; b = i / 100; tile = i - b * 100;
        p = p0; wA = wsA; bias = b0v; an = anc;
        C = 256; HW = 6400; row_off = 0; sh = 4; stride_ = 8.f;
    }
    const int hw0   = tile * 64;
    const int iters = C >> 5;            // 8 / 16 / 32, always even

    floatx4 acc[4][4];                   // [ni(hw)][mi(o)]
#pragma unroll
    for (int ni = 0; ni < 4; ++ni)
#pragma unroll
        for (int mi = 0; mi < 4; ++mi)
            acc[ni][mi] = floatx4{0.f, 0.f, 0.f, 0.f};

    const float* pb = p + (size_t)b * C * HW;
    int scol = hw0 + l; if (scol >= HW) scol = HW - 1;   // clamp (scale2 tail)
    const float* pcol0 = pb + (size_t)(wv * 8) * HW + scol;  // k-step 0 base
    const size_t kj = (size_t)32 * HW;

    // LDS chunk swizzle: row r, 16B-chunk c holds k-octet (c ^ (r&3) ^ ((r>>2)&3))
    const int wchunk = wv ^ (l & 3) ^ ((l >> 2) & 3);
    // wf base: this wave's ot range is [wv*4, wv*4+4); per-k-step stride = 16*512 shorts
    const unsigned short* wfb = wA + ((size_t)(wv * 4) << 9) + (l << 3);

    float  bvA[8], bvB[8];               // activation prefetch, 2 k-steps deep
    short8 wfA[4], wfB[4];               // weight-frag prefetch, 1 k-step deep

#define LOADBV(dst, s) do { const float* _pc = pcol0 + (size_t)(s) * kj;          \
        _Pragma("unroll") for (int _r = 0; _r < 8; ++_r)                          \
            dst[_r] = _pc[(size_t)_r * HW]; } while (0)
#define LOADWF(dst, s) do { const unsigned short* _wb = wfb + (size_t)(s) * 8192; \
        _Pragma("unroll") for (int _m = 0; _m < 4; ++_m)                          \
            dst[_m] = *(const short8*)(_wb + (_m << 9)); } while (0)
#define PACK(src, BUF) do {                                                       \
        unsigned _p0 = (unsigned)f2bf(src[0]) | ((unsigned)f2bf(src[1]) << 16);   \
        unsigned _p1 = (unsigned)f2bf(src[2]) | ((unsigned)f2bf(src[3]) << 16);   \
        unsigned _p2 = (unsigned)f2bf(src[4]) | ((unsigned)f2bf(src[5]) << 16);   \
        unsigned _p3 = (unsigned)f2bf(src[6]) | ((unsigned)f2bf(src[7]) << 16);   \
        ((uint4*)BUF)[l * 4 + wchunk] = make_uint4(_p0, _p1, _p2, _p3); } while (0)
#define READPF(pf, BUF) do { _Pragma("unroll") for (int _n = 0; _n < 4; ++_n) {   \
        int _nn = _n * 16 + ml; int _ck = q ^ (_nn & 3) ^ ((_nn >> 2) & 3);       \
        pf[_n] = *(const short8*)(BUF + _nn * 32 + _ck * 8); } } while (0)
#define MFMA16(pf, wf) do { _Pragma("unroll") for (int _n = 0; _n < 4; ++_n)      \
        _Pragma("unroll") for (int _m = 0; _m < 4; ++_m)                          \
            acc[_n][_m] = __builtin_amdgcn_mfma_f32_16x16x32_bf16(                \
                pf[_n], wf[_m], acc[_n][_m], 0, 0, 0); } while (0)
#define LGKM_BARRIER() do { asm volatile("s_waitcnt lgkmcnt(0)" ::: "memory");    \
        __builtin_amdgcn_s_barrier(); asm volatile("" ::: "memory"); } while (0)

    // ---- prologue: steps 0,1 in flight; pack 0; issue step 2 ----
    LOADBV(bvA, 0);
    LOADBV(bvB, 1);
    LOADWF(wfA, 0);
    PACK(bvA, Bl0);            // counted vmcnt: leaves bvB/wfA in flight
    LOADBV(bvA, 2);            // iters >= 8 always
    LGKM_BARRIER();

    // ---- main loop: 2 k-steps per iteration, one barrier per k-step ----
    for (int it = 0; it < iters; it += 2) {
        // phase A: compute k-step it from Bl0 / wfA
        short8 pfA[4];
        READPF(pfA, Bl0);
        PACK(bvB, Bl1);                          // k-step it+1
        if (it + 3 < iters) LOADBV(bvB, it + 3);
        LOADWF(wfB, it + 1);
        LGKM_BARRIER();
        MFMA16(pfA, wfA);

        // phase B: compute k-step it+1 from Bl1 / wfB
        short8 pfB[4];
        READPF(pfB, Bl1);
        if (it + 2 < iters) {
            PACK(bvA, Bl0);                      // k-step it+2
            if (it + 4 < iters) LOADBV(bvA, it + 4);
            LOADWF(wfA, it + 2);
            LGKM_BARRIER();
        }
        MFMA16(pfB, wfB);
    }

    // ---- epilogue: D row = hw_rel = ni*16 + q*4 + r; col = o_rel = mi*16 + ml ----
    // lanes ml=0..15 write consecutive oo -> coalesced 64B store runs
    const int nx = 5 << sh;
#pragma unroll
    for (int mi = 0; mi < 4; ++mi) {
        const int  o     = wv * 64 + mi * 16 + ml;
        const bool valid = (o < 255);
        const int  osafe = valid ? o : 254;
        const int  a     = osafe / 85;
        const int  oo    = osafe - a * 85;
        const float bi   = bias[osafe];
        const float anw  = an[a * 2 + 0];
        const float anh  = an[a * 2 + 1];
        float* orow = out + ((size_t)b * TOTAL_ROWS + row_off + a * HW) * NOUT + oo;
#pragma unroll
        for (int ni = 0; ni < 4; ++ni) {
            const int hwb = hw0 + ni * 16 + q * 4;
            if (hwb >= HW) continue;     // uniform per 16-lane group (HW % 16 == 0)
#pragma unroll
            for (int r = 0; r < 4; ++r) {
                const int hw = hwb + r;
                float y = acc[ni][mi][r] + bi;
                float s = 1.f / (1.f + __expf(-y));
                float v;
                if (oo >= 4) {
                    v = s;
                } else {
                    unsigned gy = (unsigned)(((unsigned long long)(unsigned)(hw >> sh)
                                             * 0xCCCCCCCDull) >> 34);   // (hw>>sh)/5
                    int gx = hw - (int)gy * nx;
                    if (oo == 0)      v = (2.f * s + (float)gx - 0.5f) * stride_;
                    else if (oo == 1) v = (2.f * s + (float)gy - 0.5f) * stride_;
                    else { float t = 2.f * s; v = t * t * ((oo == 2) ? anw : anh); }
                }
                if (valid) orow[(size_t)hw * NOUT] = v;
            }
        }
    }
#undef LOADBV
#undef LOADWF
#undef PACK
#undef READPF
#undef MFMA16
#undef LGKM_BARRIER
}

extern "C" void kernel_launch(void* const* d_in, const int* in_sizes, int n_in,
                              void* d_out, int out_size, void* d_ws, size_t ws_size,
                              hipStream_t stream) {
    const float* p0 = (const float*)d_in[0];
    const float* p1 = (const float*)d_in[1];
    const float* p2 = (const float*)d_in[2];
    const float* w0 = (const float*)d_in[3];
    const float* b0 = (const float*)d_in[4];
    const float* w1 = (const float*)d_in[5];
    const float* b1 = (const float*)d_in[6];
    const float* w2 = (const float*)d_in[7];
    const float* b2 = (const float*)d_in[8];
    const float* anc = (const float*)d_in[9];  // [3,3,2]
    float* out = (float*)d_out;

    unsigned short* wsA = (unsigned short*)d_ws;   // needs 917504 B

    convert_w_all<<<dim3(458752 / 256), dim3(256), 0, stream>>>(w0, w1, w2, wsA);

    // fused: 112 scale2 blocks + 400 scale1 + 1600 scale0 = 2112
    yolo_fused<<<dim3(2112), dim3(256), 0, stream>>>(
        p0, p1, p2, wsA, b0, b1, b2, anc, out);
}